// Round 1
// baseline (2829.807 us; speedup 1.0000x reference)
//
#include <hip/hip_runtime.h>
#include <hip/hip_bf16.h>
#include <math.h>

// Problem constants
constexpr int kS    = 512;
constexpr int kDim  = 2048;
constexpr int kH    = 32;
constexpr int kHK   = 4;
constexpr int kHD   = 128;
constexpr int kE    = 64;
constexpr int kTopK = 8;
constexpr int kFF   = 768;
constexpr float kEps = 1e-6f;

// GEMM tiling
constexpr int BM = 64;
constexpr int BN = 64;
constexpr int BK = 16;

// ---------------------------------------------------------------------------
// RMSNorm: one block per row
__global__ __launch_bounds__(256) void rmsnorm_kernel(
    const float* __restrict__ in, const float* __restrict__ w,
    float* __restrict__ out, int dim) {
  int t = blockIdx.x;
  const float* row = in + (size_t)t * dim;
  float ss = 0.f;
  for (int i = threadIdx.x; i < dim; i += 256) { float v = row[i]; ss += v * v; }
  for (int m = 1; m < 64; m <<= 1) ss += __shfl_xor(ss, m);
  __shared__ float red[4];
  int wid = threadIdx.x >> 6;
  if ((threadIdx.x & 63) == 0) red[wid] = ss;
  __syncthreads();
  float tot = red[0] + red[1] + red[2] + red[3];
  float r = rsqrtf(tot / (float)dim + kEps);
  for (int i = threadIdx.x; i < dim; i += 256)
    out[(size_t)t * dim + i] = row[i] * r * w[i];
}

// ---------------------------------------------------------------------------
// Generic NT GEMM: C[M,N] = A[M,K] @ B[N,K]^T (+ optional residual R[M,N])
__global__ __launch_bounds__(256) void gemm_nt_kernel(
    const float* __restrict__ A, const float* __restrict__ B,
    float* __restrict__ C, const float* __restrict__ R,
    int M, int N, int K) {
  __shared__ __align__(16) float As[BK][BM + 4];
  __shared__ __align__(16) float Bs[BK][BN + 4];
  int bm = blockIdx.y * BM, bn = blockIdx.x * BN;
  int tid = threadIdx.x;
  int tx = tid & 15, ty = tid >> 4;
  float acc[4][4] = {};
  for (int k0 = 0; k0 < K; k0 += BK) {
#pragma unroll
    for (int j = 0; j < 4; ++j) {
      int i = tid + 256 * j;
      int r = i >> 4, kk = i & 15;
      As[kk][r] = A[(size_t)(bm + r) * K + k0 + kk];
      Bs[kk][r] = B[(size_t)(bn + r) * K + k0 + kk];
    }
    __syncthreads();
#pragma unroll
    for (int kk = 0; kk < BK; ++kk) {
      float4 a = *(const float4*)&As[kk][ty * 4];
      float4 b = *(const float4*)&Bs[kk][tx * 4];
      float av[4] = {a.x, a.y, a.z, a.w};
      float bv[4] = {b.x, b.y, b.z, b.w};
#pragma unroll
      for (int i = 0; i < 4; ++i)
#pragma unroll
        for (int j = 0; j < 4; ++j) acc[i][j] += av[i] * bv[j];
    }
    __syncthreads();
  }
#pragma unroll
  for (int i = 0; i < 4; ++i) {
    int row = bm + ty * 4 + i;
#pragma unroll
    for (int j = 0; j < 4; ++j) {
      int col = bn + tx * 4 + j;
      float v = acc[i][j];
      if (R) v += R[(size_t)row * N + col];
      C[(size_t)row * N + col] = v;
    }
  }
}

// ---------------------------------------------------------------------------
// Per-(token, head) RMSNorm over HD + RoPE. One wave per row.
__global__ __launch_bounds__(64) void qknorm_rope_kernel(
    float* __restrict__ x, const float* __restrict__ w,
    const float* __restrict__ cs, const float* __restrict__ sn, int nh) {
  int t = blockIdx.x, h = blockIdx.y;
  float* row = x + ((size_t)t * nh + h) * kHD;
  int i = threadIdx.x;  // 0..63
  float a = row[i], b = row[i + 64];
  float ss = a * a + b * b;
  for (int m = 1; m < 64; m <<= 1) ss += __shfl_xor(ss, m);
  float r = rsqrtf(ss / (float)kHD + kEps);
  a = a * r * w[i];
  b = b * r * w[i + 64];
  float c0 = cs[(size_t)t * kHD + i], c1 = cs[(size_t)t * kHD + i + 64];
  float s0 = sn[(size_t)t * kHD + i], s1 = sn[(size_t)t * kHD + i + 64];
  row[i]      = a * c0 - b * s0;
  row[i + 64] = b * c1 + a * s1;
}

// ---------------------------------------------------------------------------
// Causal GQA attention, one block (128 threads) per (query, head).
__global__ __launch_bounds__(128) void attn_kernel(
    const float* __restrict__ q, const float* __restrict__ k,
    const float* __restrict__ v, float* __restrict__ o) {
  int t = blockIdx.x, h = blockIdx.y;
  int hk = h >> 3;  // H/HK = 8 query heads per kv head
  __shared__ float qv[kHD];
  __shared__ float sc[kS];
  __shared__ float red[128];
  int tid = threadIdx.x;
  if (tid < kHD) qv[tid] = q[((size_t)t * kH + h) * kHD + tid];
  __syncthreads();
  int nk = t + 1;
  const float scale = 0.08838834764831845f;  // 1/sqrt(128)
  float lmax = -1e30f;
  for (int kk = tid; kk < nk; kk += 128) {
    const float* kr = k + ((size_t)kk * kHK + hk) * kHD;
    float d = 0.f;
#pragma unroll 16
    for (int j = 0; j < kHD; ++j) d += qv[j] * kr[j];
    d *= scale;
    sc[kk] = d;
    lmax = fmaxf(lmax, d);
  }
  red[tid] = lmax;
  __syncthreads();
  for (int s2 = 64; s2 > 0; s2 >>= 1) {
    if (tid < s2) red[tid] = fmaxf(red[tid], red[tid + s2]);
    __syncthreads();
  }
  float m = red[0];
  __syncthreads();
  float lsum = 0.f;
  for (int kk = tid; kk < nk; kk += 128) {
    float p = expf(sc[kk] - m);
    sc[kk] = p;
    lsum += p;
  }
  red[tid] = lsum;
  __syncthreads();
  for (int s2 = 64; s2 > 0; s2 >>= 1) {
    if (tid < s2) red[tid] += red[tid + s2];
    __syncthreads();
  }
  float inv = 1.f / red[0];
  // pass 2: tid == output dim (blockDim == HD)
  float acc = 0.f;
  for (int kk = 0; kk < nk; ++kk)
    acc += sc[kk] * v[((size_t)kk * kHK + hk) * kHD + tid];
  o[((size_t)t * kH + h) * kHD + tid] = acc * inv;
}

// ---------------------------------------------------------------------------
// Router: logits, softmax, top-8, normalize, counts. One wave per token.
__global__ __launch_bounds__(64) void router_topk_kernel(
    const float* __restrict__ hn, const float* __restrict__ rw,
    int* __restrict__ topi, float* __restrict__ topw, int* __restrict__ counts) {
  int t = blockIdx.x;
  __shared__ __align__(16) float hrow[kDim];
  __shared__ int   sI[kTopK];
  __shared__ float sW[kTopK];
  int tid = threadIdx.x;
  for (int i = tid; i < kDim / 4; i += 64)
    ((float4*)hrow)[i] = ((const float4*)(hn + (size_t)t * kDim))[i];
  __syncthreads();
  const float* wr = rw + (size_t)tid * kDim;
  float acc = 0.f;
  for (int i = 0; i < kDim / 4; ++i) {
    float4 wv = ((const float4*)wr)[i];
    float4 hv = ((const float4*)hrow)[i];
    acc += wv.x * hv.x + wv.y * hv.y + wv.z * hv.z + wv.w * hv.w;
  }
  float mx = acc;
  for (int m = 1; m < 64; m <<= 1) mx = fmaxf(mx, __shfl_xor(mx, m));
  float ex = expf(acc - mx);
  float sm = ex;
  for (int m = 1; m < 64; m <<= 1) sm += __shfl_xor(sm, m);
  float val = ex / sm;  // this lane's prob
  for (int r = 0; r < kTopK; ++r) {
    float v = val;
    int idx = tid;
    for (int m = 1; m < 64; m <<= 1) {
      float ov = __shfl_xor(v, m);
      int oi = __shfl_xor(idx, m);
      if (ov > v || (ov == v && oi < idx)) { v = ov; idx = oi; }
    }
    if (tid == idx) val = -1.f;
    if (tid == 0) { sI[r] = idx; sW[r] = v; }
  }
  __syncthreads();
  float wsum = 0.f;
  for (int r = 0; r < kTopK; ++r) wsum += sW[r];
  float invs = 1.f / (wsum + 1e-20f);
  if (tid < kTopK) {
    topi[t * kTopK + tid] = sI[tid];
    topw[t * kTopK + tid] = sW[tid] * invs;
    atomicAdd(&counts[sI[tid]], 1);
  }
}

// ---------------------------------------------------------------------------
__global__ void scan_offsets_kernel(const int* __restrict__ counts,
                                    int* __restrict__ offsets,
                                    int* __restrict__ cursor) {
  if (threadIdx.x == 0) {
    int run = 0;
    for (int e = 0; e < kE; ++e) {
      offsets[e] = run;
      cursor[e] = run;
      run += counts[e];
    }
  }
}

__global__ __launch_bounds__(256) void scatter_kernel(
    const int* __restrict__ topi, const float* __restrict__ topw,
    int* __restrict__ cursor, int* __restrict__ slot_token,
    float* __restrict__ slot_w) {
  int t = blockIdx.x * 256 + threadIdx.x;
  if (t >= kS) return;
  for (int r = 0; r < kTopK; ++r) {
    int e = topi[t * kTopK + r];
    int s = atomicAdd(&cursor[e], 1);
    slot_token[s] = t;
    slot_w[s] = topw[t * kTopK + r];
  }
}

// ---------------------------------------------------------------------------
// MoE gate+up grouped GEMM with SiLU: mid[slot, f] = silu(g) * u
__global__ __launch_bounds__(256) void moe_mid_kernel(
    const float* __restrict__ hn, const float* __restrict__ gate_w,
    const float* __restrict__ up_w, const int* __restrict__ offsets,
    const int* __restrict__ counts, const int* __restrict__ slot_token,
    float* __restrict__ mid) {
  int e = blockIdx.x;
  int f0 = blockIdx.y * BN;  // FF/BN = 12 tiles
  int off = offsets[e], n = counts[e];
  if (n == 0) return;
  __shared__ __align__(16) float As[BK][BM + 4];
  __shared__ __align__(16) float Gs[BK][BN + 4];
  __shared__ __align__(16) float Us[BK][BN + 4];
  __shared__ int toks[BM];
  const float* G = gate_w + (size_t)e * kFF * kDim;
  const float* U = up_w + (size_t)e * kFF * kDim;
  int tid = threadIdx.x;
  int tx = tid & 15, ty = tid >> 4;
  for (int t0 = 0; t0 < n; t0 += BM) {
    __syncthreads();
    if (tid < BM) {
      int r = t0 + tid;
      toks[tid] = slot_token[off + (r < n ? r : n - 1)];
    }
    __syncthreads();
    float accg[4][4] = {};
    float accu[4][4] = {};
    for (int k0 = 0; k0 < kDim; k0 += BK) {
#pragma unroll
      for (int j = 0; j < 4; ++j) {
        int i = tid + 256 * j;
        int r = i >> 4, kk = i & 15;
        As[kk][r] = hn[(size_t)toks[r] * kDim + k0 + kk];
        Gs[kk][r] = G[(size_t)(f0 + r) * kDim + k0 + kk];
        Us[kk][r] = U[(size_t)(f0 + r) * kDim + k0 + kk];
      }
      __syncthreads();
#pragma unroll
      for (int kk = 0; kk < BK; ++kk) {
        float4 a = *(const float4*)&As[kk][ty * 4];
        float4 g = *(const float4*)&Gs[kk][tx * 4];
        float4 u = *(const float4*)&Us[kk][tx * 4];
        float av[4] = {a.x, a.y, a.z, a.w};
        float gv[4] = {g.x, g.y, g.z, g.w};
        float uv[4] = {u.x, u.y, u.z, u.w};
#pragma unroll
        for (int i = 0; i < 4; ++i)
#pragma unroll
          for (int j = 0; j < 4; ++j) {
            accg[i][j] += av[i] * gv[j];
            accu[i][j] += av[i] * uv[j];
          }
      }
      __syncthreads();
    }
#pragma unroll
    for (int i = 0; i < 4; ++i) {
      int lr = t0 + ty * 4 + i;
      if (lr < n) {
        size_t srow = (size_t)(off + lr) * kFF;
#pragma unroll
        for (int j = 0; j < 4; ++j) {
          float g = accg[i][j], u = accu[i][j];
          float mval = g / (1.f + expf(-g)) * u;
          mid[srow + f0 + tx * 4 + j] = mval;
        }
      }
    }
  }
}

// ---------------------------------------------------------------------------
// MoE down grouped GEMM: out[t, d] += w_slot * (mid[slot] @ down_w[e].T)
__global__ __launch_bounds__(256) void moe_down_kernel(
    const float* __restrict__ mid, const float* __restrict__ down_w,
    const int* __restrict__ offsets, const int* __restrict__ counts,
    const int* __restrict__ slot_token, const float* __restrict__ slot_w,
    float* __restrict__ out) {
  int e = blockIdx.x;
  int d0 = blockIdx.y * BN;  // DIM/BN = 32 tiles
  int off = offsets[e], n = counts[e];
  if (n == 0) return;
  __shared__ __align__(16) float As[BK][BM + 4];
  __shared__ __align__(16) float Bs[BK][BN + 4];
  const float* D = down_w + (size_t)e * kDim * kFF;
  int tid = threadIdx.x;
  int tx = tid & 15, ty = tid >> 4;
  for (int t0 = 0; t0 < n; t0 += BM) {
    float acc[4][4] = {};
    for (int k0 = 0; k0 < kFF; k0 += BK) {
#pragma unroll
      for (int j = 0; j < 4; ++j) {
        int i = tid + 256 * j;
        int r = i >> 4, kk = i & 15;
        int rr = t0 + r; if (rr >= n) rr = n - 1;
        As[kk][r] = mid[(size_t)(off + rr) * kFF + k0 + kk];
        Bs[kk][r] = D[(size_t)(d0 + r) * kFF + k0 + kk];
      }
      __syncthreads();
#pragma unroll
      for (int kk = 0; kk < BK; ++kk) {
        float4 a = *(const float4*)&As[kk][ty * 4];
        float4 b = *(const float4*)&Bs[kk][tx * 4];
        float av[4] = {a.x, a.y, a.z, a.w};
        float bv[4] = {b.x, b.y, b.z, b.w};
#pragma unroll
        for (int i = 0; i < 4; ++i)
#pragma unroll
          for (int j = 0; j < 4; ++j) acc[i][j] += av[i] * bv[j];
      }
      __syncthreads();
    }
#pragma unroll
    for (int i = 0; i < 4; ++i) {
      int lr = t0 + ty * 4 + i;
      if (lr < n) {
        int s = off + lr;
        int t = slot_token[s];
        float w = slot_w[s];
#pragma unroll
        for (int j = 0; j < 4; ++j)
          atomicAdd(&out[(size_t)t * kDim + d0 + tx * 4 + j], w * acc[i][j]);
      }
    }
  }
}

// ---------------------------------------------------------------------------
extern "C" void kernel_launch(void* const* d_in, const int* in_sizes, int n_in,
                              void* d_out, int out_size, void* d_ws, size_t ws_size,
                              hipStream_t stream) {
  const float* x        = (const float*)d_in[0];
  const float* cosb     = (const float*)d_in[1];
  const float* sinb     = (const float*)d_in[2];
  const float* norm1_w  = (const float*)d_in[3];
  const float* wq       = (const float*)d_in[4];
  const float* wk       = (const float*)d_in[5];
  const float* wv       = (const float*)d_in[6];
  const float* wo       = (const float*)d_in[7];
  const float* q_norm_w = (const float*)d_in[8];
  const float* k_norm_w = (const float*)d_in[9];
  const float* norm2_w  = (const float*)d_in[10];
  const float* router_w = (const float*)d_in[11];
  const float* gate_w   = (const float*)d_in[12];
  const float* up_w     = (const float*)d_in[13];
  const float* down_w   = (const float*)d_in[14];
  float* out = (float*)d_out;

  // Workspace layout (floats)
  float* ws = (float*)d_ws;
  float* xn   = ws;                       // 512*2048
  float* qb   = xn + kS * kDim;           // 512*4096
  float* kb   = qb + kS * kH * kHD;       // 512*512
  float* vb   = kb + kS * kHK * kHD;      // 512*512
  float* ab   = vb + kS * kHK * kHD;      // 512*4096
  float* hb   = ab + kS * kH * kHD;       // 512*2048
  float* hnb  = hb + kS * kDim;           // 512*2048
  float* mid  = hnb + kS * kDim;          // 4096*768
  float* topw = mid + (size_t)kS * kTopK * kFF;  // 512*8
  float* slotw = topw + kS * kTopK;       // 4096
  int* topi       = (int*)(slotw + kS * kTopK);
  int* slot_token = topi + kS * kTopK;
  int* counts     = slot_token + kS * kTopK;
  int* offsets    = counts + kE;
  int* cursor     = offsets + kE;

  // 1. pre-attention norm
  rmsnorm_kernel<<<kS, 256, 0, stream>>>(x, norm1_w, xn, kDim);
  // 2-4. QKV projections
  gemm_nt_kernel<<<dim3(kH * kHD / BN, kS / BM), 256, 0, stream>>>(
      xn, wq, qb, nullptr, kS, kH * kHD, kDim);
  gemm_nt_kernel<<<dim3(kHK * kHD / BN, kS / BM), 256, 0, stream>>>(
      xn, wk, kb, nullptr, kS, kHK * kHD, kDim);
  gemm_nt_kernel<<<dim3(kHK * kHD / BN, kS / BM), 256, 0, stream>>>(
      xn, wv, vb, nullptr, kS, kHK * kHD, kDim);
  // 5-6. qk-norm + RoPE
  qknorm_rope_kernel<<<dim3(kS, kH), 64, 0, stream>>>(qb, q_norm_w, cosb, sinb, kH);
  qknorm_rope_kernel<<<dim3(kS, kHK), 64, 0, stream>>>(kb, k_norm_w, cosb, sinb, kHK);
  // 7. attention
  attn_kernel<<<dim3(kS, kH), 128, 0, stream>>>(qb, kb, vb, ab);
  // 8. output projection + residual
  gemm_nt_kernel<<<dim3(kDim / BN, kS / BM), 256, 0, stream>>>(
      ab, wo, hb, x, kS, kDim, kH * kHD);
  // 9. post-attention norm
  rmsnorm_kernel<<<kS, 256, 0, stream>>>(hb, norm2_w, hnb, kDim);
  // 10. router + top-k
  hipMemsetAsync(counts, 0, kE * sizeof(int), stream);
  router_topk_kernel<<<kS, 64, 0, stream>>>(hnb, router_w, topi, topw, counts);
  // 11-12. build expert groups
  scan_offsets_kernel<<<1, 64, 0, stream>>>(counts, offsets, cursor);
  scatter_kernel<<<(kS + 255) / 256, 256, 0, stream>>>(topi, topw, cursor,
                                                       slot_token, slotw);
  // 13. gate/up + silu
  moe_mid_kernel<<<dim3(kE, kFF / BN), 256, 0, stream>>>(
      hnb, gate_w, up_w, offsets, counts, slot_token, mid);
  // 14. out = h (then down-proj accumulates into it)
  hipMemcpyAsync(out, hb, (size_t)kS * kDim * sizeof(float),
                 hipMemcpyDeviceToDevice, stream);
  // 15. down projection + weighted combine
  moe_down_kernel<<<dim3(kE, kDim / BN), 256, 0, stream>>>(
      mid, down_w, offsets, counts, slot_token, slotw, out);
}